// Round 16
// baseline (103.059 us; speedup 1.0000x reference)
//
#include <hip/hip_runtime.h>

// Problem constants
#define B_    2
#define S_    2048
#define DIN   1024
#define DOUT  1024
#define H_    16
#define HD_   64
#define M_    (B_ * S_)   // 4096 rows total

typedef __bf16 bf16x8 __attribute__((ext_vector_type(8)));
typedef float  f32x4  __attribute__((ext_vector_type(4)));

__device__ __forceinline__ f32x4 MFMA(bf16x8 a, bf16x8 b, f32x4 c) {
    return __builtin_amdgcn_mfma_f32_16x16x32_bf16(a, b, c, 0, 0, 0);
}

// float -> bf16 bits, round-to-nearest-even
__device__ __forceinline__ unsigned short f2b(float f) {
    union { float f; unsigned int u; } v; v.f = f;
    unsigned int u = v.u;
    return (unsigned short)((u + 0x7fffu + ((u >> 16) & 1u)) >> 16);
}

// pack two floats into one u32 of bf16 pairs (lo = a, hi = b)
__device__ __forceinline__ unsigned pack2(float a, float b) {
    union { __bf16 h[2]; unsigned u; } cv;
    cv.h[0] = (__bf16)a; cv.h[1] = (__bf16)b;
    return cv.u;
}

// async global->LDS, 16B per lane; LDS dest = wave-uniform base + lane*16
#define GLDS(gp, lp) __builtin_amdgcn_global_load_lds( \
    (const __attribute__((address_space(1))) void*)(gp), \
    (__attribute__((address_space(3))) void*)(lp), 16, 0, 0)

// Q pre-scale: 1/sqrt(64) * log2(e)  (exp2-domain softmax)
#define QSCALE 0.1803368801111204f

// ---- fused converts, vectorized ----
// grid [0,1024): x f32->bf16, 16 elems/thread.
// grid [1024,2048): weight transpose 64x64 f32 tiles, float4 in / ushort8 out.
// Transpose-read conflict fix: column-group XOR'd with row>>3 (both sides).
__global__ __launch_bounds__(256) void k_cvt_all(const float* __restrict__ x,
                                                 const float* __restrict__ Wq,
                                                 const float* __restrict__ Wk,
                                                 const float* __restrict__ Wv,
                                                 const float* __restrict__ Wo,
                                                 unsigned short* __restrict__ xb,
                                                 unsigned short* __restrict__ WqkvT,
                                                 unsigned short* __restrict__ WoT) {
    __shared__ __align__(16) float tile[64][68];
    int bid = blockIdx.x;
    int tid = threadIdx.x;
    if (bid < 1024) {
#pragma unroll
        for (int j = 0; j < 4; j++) {
            int i = bid * 4096 + j * 1024 + tid * 4;
            float4 v = *reinterpret_cast<const float4*>(x + i);
            ushort4 o;
            o.x = f2b(v.x); o.y = f2b(v.y); o.z = f2b(v.z); o.w = f2b(v.w);
            *reinterpret_cast<ushort4*>(xb + i) = o;
        }
        return;
    }
    int wb = bid - 1024;
    int w = wb >> 8;                        // which weight 0..3
    int t = wb & 255;                       // 64x64 tile over 1024^2
    const float* src = (w == 0) ? Wq : (w == 1) ? Wk : (w == 2) ? Wv : Wo;
    unsigned short* dst = (w < 3) ? WqkvT + (size_t)w * 1024 * DIN : WoT;
    int k0 = (t >> 4) * 64, n0 = (t & 15) * 64;
    // load 64 k-rows x 64 n f32; store col-group swizzled by (r>>3)
#pragma unroll
    for (int j = 0; j < 4; j++) {
        int idx = j * 256 + tid;
        int r = idx >> 4, c4g = idx & 15;
        int sg = c4g ^ ((r >> 3) & 7);
        *reinterpret_cast<float4*>(&tile[r][sg * 4]) =
            *reinterpret_cast<const float4*>(&src[(size_t)(k0 + r) * DOUT + n0 + c4g * 4]);
    }
    __syncthreads();
    // store transposed: element (k, n) lives at tile[k][((n>>2)^(k>>3))*4 + (n&3)]
#pragma unroll
    for (int j = 0; j < 2; j++) {
        int idx = j * 256 + tid;
        int n = idx >> 3, gk = (idx & 7) * 8;
        int g = n >> 2, e = n & 3;
        unsigned short o[8];
#pragma unroll
        for (int u = 0; u < 8; u++) {
            int k = gk + u;
            o[u] = f2b(tile[k][((g ^ ((k >> 3) & 7)) << 2) + e]);
        }
        *reinterpret_cast<int4*>(&dst[(size_t)(n0 + n) * DIN + k0 + gk]) =
            *reinterpret_cast<int4*>(o);
    }
}

// ---------------- bf16 MFMA GEMM: C[M,N] = A[M,K] @ Bt[N,K]^T ----------------
// BM x 128 tile, BK=32, QUAD-buffered global_load_lds staging with counted
// vmcnt (T4): stage(kt+2) two tiles ahead, single barrier per K-step, waits
// vmcnt(2L)/(L)/(0) — next-tile loads stay in flight across the barrier.
// Race-free: stage(kt+2) overwrites buf(kt-2), whose last reader compute(kt-2)
// precedes barrier(kt-1) in every wave's program order. T2 XOR swizzle.
// OUT_MODE 0: QKV fused — Q/K row-major bf16 (Q pre-scaled by QSCALE);
//             V blocks written TRANSPOSED to Cvt[(b*16+h)*64+hd][s] via LDS.
// OUT_MODE 2: f32 out + bias.
template <int OUT_MODE, int BM>
__global__ __launch_bounds__(256) void k_gemm(const unsigned short* __restrict__ A,
                                              const unsigned short* __restrict__ Bt,
                                              unsigned short* __restrict__ Cq,
                                              unsigned short* __restrict__ Ck,
                                              unsigned short* __restrict__ Cvt,
                                              float* __restrict__ Cf,
                                              const float* __restrict__ bias,
                                              int M, int N, int K, int nbx) {
    constexpr int MI  = BM / 32;            // M-frags per wave
    constexpr int ASZ = BM * 32;            // ushorts per A buffer
    constexpr int BSZ = 128 * 32;
    constexpr int ACH = BM / 64;            // A chunks per wave (1KB each)
    constexpr int STG = 4 * (ASZ + BSZ);    // quad-buffered
    constexpr int SMEM_N = (OUT_MODE == 0 && STG < 17408) ? 17408 : STG;
    __shared__ __align__(16) unsigned short smem[SMEM_N];

    int nwg = gridDim.x;
    int chunkw = nwg >> 3;
    int bid = blockIdx.x;
    int nid = (bid & 7) * chunkw + (bid >> 3);
    int by = nid / nbx, bx = nid - by * nbx;
    int m0 = by * BM, n0 = bx * 128;

    int tid = threadIdx.x;
    int wid = tid >> 6, lane = tid & 63;
    int wm = wid >> 1, wn = wid & 1;
    int lr = lane & 15, lg = lane >> 4;

    f32x4 acc[MI][4] = {};

    int srow = lane >> 2;                           // 0..15 within chunk
    int scol = ((lane & 3) ^ (srow & 3)) * 8;       // pre-swizzled source col
    int runit = (lg ^ (lr & 3)) * 8;                // read-side unit offset

#define STAGE_G(buf, k0)                                                       \
    {                                                                          \
        unsigned short* Ad = smem + (buf) * ASZ;                               \
        unsigned short* Bd = smem + 4 * ASZ + (buf) * BSZ;                     \
        _Pragma("unroll")                                                      \
        for (int c = 0; c < ACH; c++) {                                        \
            int chunk = wid * ACH + c;                                         \
            int row = chunk * 16 + srow;                                       \
            GLDS(A + (size_t)(m0 + row) * K + (k0) + scol,                     \
                 (char*)Ad + chunk * 1024);                                    \
        }                                                                      \
        _Pragma("unroll")                                                      \
        for (int c = 0; c < 2; c++) {                                          \
            int chunk = wid * 2 + c;                                           \
            int row = chunk * 16 + srow;                                       \
            GLDS(Bt + (size_t)(n0 + row) * K + (k0) + scol,                    \
                 (char*)Bd + chunk * 1024);                                    \
        }                                                                      \
    }

    int nkt = K >> 5;
    STAGE_G(0, 0)
    STAGE_G(1, 32)

    for (int kt = 0; kt < nkt; kt++) {
        int buf = kt & 3;
        int ahead = nkt - 1 - kt;
        if (ahead >= 2) {
            STAGE_G((kt + 2) & 3, (kt + 2) * 32)
            if constexpr (BM == 128) { asm volatile("s_waitcnt vmcnt(8)" ::: "memory"); }
            else                     { asm volatile("s_waitcnt vmcnt(6)" ::: "memory"); }
        } else if (ahead == 1) {
            if constexpr (BM == 128) { asm volatile("s_waitcnt vmcnt(4)" ::: "memory"); }
            else                     { asm volatile("s_waitcnt vmcnt(3)" ::: "memory"); }
        } else {
            asm volatile("s_waitcnt vmcnt(0)" ::: "memory");
        }
        __builtin_amdgcn_s_barrier();

        const unsigned short* Asr = smem + buf * ASZ;
        const unsigned short* Bsr = smem + 4 * ASZ + buf * BSZ;
        bf16x8 af[MI], bf[4];
#pragma unroll
        for (int mi = 0; mi < MI; mi++)
            af[mi] = *reinterpret_cast<const bf16x8*>(
                &Asr[(wm * (BM / 2) + mi * 16 + lr) * 32 + runit]);
#pragma unroll
        for (int ni = 0; ni < 4; ni++)
            bf[ni] = *reinterpret_cast<const bf16x8*>(
                &Bsr[(wn * 64 + ni * 16 + lr) * 32 + runit]);
#pragma unroll
        for (int mi = 0; mi < MI; mi++)
#pragma unroll
            for (int ni = 0; ni < 4; ni++)
                acc[mi][ni] = MFMA(af[mi], bf[ni], acc[mi][ni]);
    }

    if (OUT_MODE == 2) {
        for (int mi = 0; mi < MI; mi++)
            for (int ni = 0; ni < 4; ni++)
                for (int i = 0; i < 4; i++) {
                    int row = m0 + wm * (BM / 2) + mi * 16 + lg * 4 + i;
                    int col = n0 + wn * 64 + ni * 16 + lr;
                    Cf[(size_t)row * N + col] = acc[mi][ni][i] + bias[col];
                }
    } else if (n0 < 2048) {
        unsigned short* Cd = (n0 < 1024) ? Cq : Ck;
        int cb = (n0 < 1024) ? 0 : 1024;
        float sc = (n0 < 1024) ? QSCALE : 1.0f;
        for (int mi = 0; mi < MI; mi++)
            for (int ni = 0; ni < 4; ni++)
                for (int i = 0; i < 4; i++) {
                    int row = m0 + wm * (BM / 2) + mi * 16 + lg * 4 + i;
                    int col = n0 + wn * 64 + ni * 16 + lr;
                    Cd[(size_t)row * 1024 + (col - cb)] = f2b(acc[mi][ni][i] * sc);
                }
    } else {
        // V: transpose through LDS (Lt[128 cols][136 rows bf16]) then write
        // coalesced rows of Cvt[(b*16+h)*64+hd][s]. Lt overlaps staging
        // buffers other waves may still be reading -> barrier first.
        __syncthreads();
        unsigned short* Lt = smem;
        for (int mi = 0; mi < MI; mi++)
            for (int ni = 0; ni < 4; ni++) {
                int cl = wn * 64 + ni * 16 + lr;
                int rl0 = wm * (BM / 2) + mi * 16 + lg * 4;
                uint2 wd;
                wd.x = pack2(acc[mi][ni][0], acc[mi][ni][1]);
                wd.y = pack2(acc[mi][ni][2], acc[mi][ni][3]);
                *reinterpret_cast<uint2*>(&Lt[cl * 136 + rl0]) = wd;
            }
        __syncthreads();
        int b = m0 >> 11, ms = m0 & (S_ - 1);
        int bh64 = (b * H_ + ((n0 - 2048) >> 6)) * 64;
#pragma unroll
        for (int it = 0; it < 4; it++) {
            int cl = it * 32 + (tid >> 3);
            int ss = (tid & 7) * 16;
            int4 v0 = *reinterpret_cast<int4*>(&Lt[cl * 136 + ss]);
            int4 v1 = *reinterpret_cast<int4*>(&Lt[cl * 136 + ss + 8]);
            unsigned short* dp = Cvt + (size_t)(bh64 + cl) * S_ + ms + ss;
            *reinterpret_cast<int4*>(dp) = v0;
            *reinterpret_cast<int4*>(dp + 8) = v1;
        }
    }
#undef STAGE_G
}

// ---------------- flash attention (causal), 8-wave paired blocks ----------------
// 1-D grid of 512 blocks with XCD-aware (T1) bijective swizzle: with the
// hardware's bid%8 round-robin, xcd = bid&7 selects a group of 4 bh, so each
// XCD's 64 resident blocks share 4 heads -> KV working set 2MB <= 4MB L2.
// Waves 0-3: q-tile 31-p; waves 4-7: q-tile p. QUAD-buffered KV stream,
// single barrier per iteration (race-free: stage(t+2) writes buf((t-2)%4)
// whose last reader precedes barrier(t-1) in program order). vmcnt counted.
// Boundless exp2-softmax, per-lane l accumulation.
__global__ __launch_bounds__(512, 4) void k_attn(const unsigned short* __restrict__ Q,
                                                 const unsigned short* __restrict__ Kg,
                                                 const unsigned short* __restrict__ Vt,
                                                 unsigned short* __restrict__ ctx) {
    int bid = blockIdx.x;
    int xcd = bid & 7;
    int k   = bid >> 3;          // 0..63
    int p   = k >> 2;            // 0..15
    int bh  = xcd * 4 + (k & 3); // 0..31, grouped 4-per-XCD
    int b = bh >> 4, h = bh & 15;
    int tid = threadIdx.x, wid = tid >> 6, lane = tid & 63;
    int lr = lane & 15, lg = lane >> 4;
    int qtB = 31 - p;
    int qt = (wid < 4) ? qtB : p;          // wave's own q-tile
    int q0 = qt * 64 + (wid & 3) * 16;     // wave's 16 q-rows

    __shared__ __align__(16) unsigned short Ks[4][64 * 64];   // [kv][hd], swizzled
    __shared__ __align__(16) unsigned short Vs[4][64 * 64];   // [hd][s],  swizzled
    __shared__ __align__(16) unsigned p_lds32[8][16 * 32];    // per-wave P
    unsigned* pl32 = p_lds32[wid];

    const unsigned short* Qp = Q  + (size_t)b * S_ * DOUT + (size_t)h * HD_;
    const unsigned short* Kp = Kg + (size_t)b * S_ * DOUT + (size_t)h * HD_;
    const unsigned short* Vp = Vt + (size_t)(b * H_ + h) * HD_ * S_;

    bf16x8 qf0 = *reinterpret_cast<const bf16x8*>(&Qp[(size_t)(q0 + lr) * DOUT + lg * 8]);
    bf16x8 qf1 = *reinterpret_cast<const bf16x8*>(&Qp[(size_t)(q0 + lr) * DOUT + 32 + lg * 8]);
    asm volatile("" : "+v"(qf0), "+v"(qf1));

    int srow = lane >> 3;
    int scol = ((lane & 7) ^ srow) * 8;        // pre-swizzled col (elements)

#define STAGE_KV(buf, t)                                                           \
    {                                                                              \
        int kv0_ = (t) * 64;                                                       \
        int krow = wid * 8 + srow;                                                 \
        GLDS(Kp + (size_t)(kv0_ + krow) * DOUT + scol,                             \
             (char*)&Ks[buf][0] + wid * 1024);                                     \
        GLDS(Vp + (size_t)krow * S_ + kv0_ + scol,                                 \
             (char*)&Vs[buf][0] + wid * 1024);                                     \
    }

    int ntile = qtB + 1;   // >= 17
    STAGE_KV(0, 0)
    STAGE_KV(1, 1)

    f32x4 o[4] = {};
    float l = 0.f;
    int rxor = (lr & 7) << 4;
    int qg = q0 + lr;

    int cur = 0;           // t % 4
    for (int t = 0; t < ntile; t++) {
        int ahead = ntile - 1 - t;
        if (ahead >= 2) {
            STAGE_KV((cur + 2) & 3, t + 2)
            asm volatile("s_waitcnt vmcnt(4)" ::: "memory");
        } else if (ahead == 1) {
            asm volatile("s_waitcnt vmcnt(2)" ::: "memory");
        } else {
            asm volatile("s_waitcnt vmcnt(0)" ::: "memory");
        }
        __builtin_amdgcn_s_barrier();

        if (t <= qt) {
            const unsigned short* Kt = Ks[cur];
            const unsigned short* Vl = Vs[cur];
            int kv0 = t * 64;

            // QK^T swapped: mfma(K, Q) -> lane owns q-row (q0+lr)
            f32x4 s[4] = {};
            __builtin_amdgcn_s_setprio(1);
#pragma unroll
            for (int nf = 0; nf < 4; nf++)
#pragma unroll
                for (int kk = 0; kk < 2; kk++) {
                    bf16x8 kf = *reinterpret_cast<const bf16x8*>(
                        &Kt[(nf * 16 + lr) * 64 + (((kk * 64 + lg * 16) ^ rxor) >> 1)]);
                    s[nf] = MFMA(kf, kk ? qf1 : qf0, s[nf]);
                }
            __builtin_amdgcn_s_setprio(0);

            if (t == qt) {
#pragma unroll
                for (int nf = 0; nf < 4; nf++)
#pragma unroll
                    for (int i = 0; i < 4; i++)
                        if (kv0 + nf * 16 + lg * 4 + i > qg) s[nf][i] = -2000.0f;
            }

            // boundless softmax: P = exp2(s), pack to bf16, swizzled P-LDS
            f32x4 acc = {};
#pragma unroll
            for (int nf = 0; nf < 4; nf++) {
                f32x4 pv;
#pragma unroll
                for (int i = 0; i < 4; i++) pv[i] = exp2f(s[nf][i]);
                acc += pv;
                int unit = (nf * 2 + (lg >> 1)) ^ (lr & 7);
                uint2 wd; wd.x = pack2(pv[0], pv[1]); wd.y = pack2(pv[2], pv[3]);
                *reinterpret_cast<uint2*>(&pl32[lr * 32 + unit * 4 + (lg & 1) * 2]) = wd;
            }
            l += (acc[0] + acc[1]) + (acc[2] + acc[3]);

            bf16x8 pf[2];
#pragma unroll
            for (int kvb = 0; kvb < 2; kvb++)
                pf[kvb] = *reinterpret_cast<const bf16x8*>(
                    &pl32[lr * 32 + (((kvb * 4 + lg) ^ (lr & 7)) * 4)]);

            // PV
            __builtin_amdgcn_s_setprio(1);
#pragma unroll
            for (int nd = 0; nd < 4; nd++)
#pragma unroll
                for (int kk = 0; kk < 2; kk++) {
                    bf16x8 vf = *reinterpret_cast<const bf16x8*>(
                        &Vl[(nd * 16 + lr) * 64 + (((kk * 64 + lg * 16) ^ rxor) >> 1)]);
                    o[nd] = MFMA(pf[kk], vf, o[nd]);
                }
            __builtin_amdgcn_s_setprio(0);
        }

        cur = (cur + 1) & 3;
    }

    // cross-lane row sums (hoisted out of the KV loop)
    l += __shfl_xor(l, 16, 64);
    l += __shfl_xor(l, 32, 64);

#pragma unroll
    for (int i = 0; i < 4; i++) {
        float li = __shfl(l, lg * 4 + i, 16);
        float r = __builtin_amdgcn_rcpf(li);
#pragma unroll
        for (int nd = 0; nd < 4; nd++)
            ((__bf16*)ctx)[((size_t)b * S_ + q0 + lg * 4 + i) * DOUT + h * HD_ + nd * 16 + lr] =
                (__bf16)(o[nd][i] * r);
    }
#undef STAGE_KV
}

extern "C" void kernel_launch(void* const* d_in, const int* in_sizes, int n_in,
                              void* d_out, int out_size, void* d_ws, size_t ws_size,
                              hipStream_t stream) {
    const float* x  = (const float*)d_in[0];
    const float* Wq = (const float*)d_in[1];
    const float* Wk = (const float*)d_in[2];
    const float* Wv = (const float*)d_in[3];
    const float* Wo = (const float*)d_in[4];
    const float* bo = (const float*)d_in[5];
    float* out = (float*)d_out;
    char* ws = (char*)d_ws;
    const size_t MB = 1u << 20;

    // layout (40 MB): xb@0 (ctx reuses after QKV), WqkvT@8, WoT@14,
    // Qb@16, Kb@24, Vtb@32 (written transposed by QKV epilogue).
    unsigned short* xb    = (unsigned short*)(ws);
    unsigned short* ctx   = (unsigned short*)(ws);            // reuse of xb
    unsigned short* WqkvT = (unsigned short*)(ws + 8 * MB);
    unsigned short* WoT   = (unsigned short*)(ws + 14 * MB);
    unsigned short* Qb    = (unsigned short*)(ws + 16 * MB);
    unsigned short* Kb    = (unsigned short*)(ws + 24 * MB);
    unsigned short* Vtb   = (unsigned short*)(ws + 32 * MB);

    (void)in_sizes; (void)n_in; (void)out_size; (void)ws_size;

    // fused converts: x -> bf16, 4 weights -> bf16 transposed
    k_cvt_all<<<2048, 256, 0, stream>>>(x, Wq, Wk, Wv, Wo, xb, WqkvT, WoT);

    // fused QKV projection (Q pre-scaled; V written transposed -> no trV pass)
    k_gemm<0, 128><<<768, 256, 0, stream>>>(xb, WqkvT, Qb, Kb, Vtb, nullptr, nullptr,
                                            M_, 3072, DIN, 24);

    // causal flash attention: XCD-swizzled 1-D grid, quad-buffered single-barrier
    k_attn<<<512, 512, 0, stream>>>(Qb, Kb, Vtb, ctx);

    // output projection + bias (BM=64 tile -> 512 blocks = 2/CU)
    k_gemm<2, 64><<<512, 256, 0, stream>>>(ctx, WoT, nullptr, nullptr, nullptr,
                                           out, bo, M_, DOUT, DOUT, 8);
}

// Round 17
// 101.026 us; speedup vs baseline: 1.0201x; 1.0201x over previous
//
#include <hip/hip_runtime.h>

// Problem constants
#define B_    2
#define S_    2048
#define DIN   1024
#define DOUT  1024
#define H_    16
#define HD_   64
#define M_    (B_ * S_)   // 4096 rows total

typedef __bf16 bf16x8 __attribute__((ext_vector_type(8)));
typedef float  f32x4  __attribute__((ext_vector_type(4)));

__device__ __forceinline__ f32x4 MFMA(bf16x8 a, bf16x8 b, f32x4 c) {
    return __builtin_amdgcn_mfma_f32_16x16x32_bf16(a, b, c, 0, 0, 0);
}

// float -> bf16 bits, round-to-nearest-even
__device__ __forceinline__ unsigned short f2b(float f) {
    union { float f; unsigned int u; } v; v.f = f;
    unsigned int u = v.u;
    return (unsigned short)((u + 0x7fffu + ((u >> 16) & 1u)) >> 16);
}

// pack two floats into one u32 of bf16 pairs (lo = a, hi = b)
__device__ __forceinline__ unsigned pack2(float a, float b) {
    union { __bf16 h[2]; unsigned u; } cv;
    cv.h[0] = (__bf16)a; cv.h[1] = (__bf16)b;
    return cv.u;
}

// async global->LDS, 16B per lane; LDS dest = wave-uniform base + lane*16
#define GLDS(gp, lp) __builtin_amdgcn_global_load_lds( \
    (const __attribute__((address_space(1))) void*)(gp), \
    (__attribute__((address_space(3))) void*)(lp), 16, 0, 0)

// Q pre-scale: 1/sqrt(64) * log2(e)  (exp2-domain softmax)
#define QSCALE 0.1803368801111204f

// ---- fused converts, vectorized ----
// grid [0,1024): x f32->bf16, 16 elems/thread.
// grid [1024,2048): weight transpose 64x64 f32 tiles, float4 in / ushort8 out.
// Transpose-read conflict fix: column-group XOR'd with row>>3 (both sides).
__global__ __launch_bounds__(256) void k_cvt_all(const float* __restrict__ x,
                                                 const float* __restrict__ Wq,
                                                 const float* __restrict__ Wk,
                                                 const float* __restrict__ Wv,
                                                 const float* __restrict__ Wo,
                                                 unsigned short* __restrict__ xb,
                                                 unsigned short* __restrict__ WqkvT,
                                                 unsigned short* __restrict__ WoT) {
    __shared__ __align__(16) float tile[64][68];
    int bid = blockIdx.x;
    int tid = threadIdx.x;
    if (bid < 1024) {
#pragma unroll
        for (int j = 0; j < 4; j++) {
            int i = bid * 4096 + j * 1024 + tid * 4;
            float4 v = *reinterpret_cast<const float4*>(x + i);
            ushort4 o;
            o.x = f2b(v.x); o.y = f2b(v.y); o.z = f2b(v.z); o.w = f2b(v.w);
            *reinterpret_cast<ushort4*>(xb + i) = o;
        }
        return;
    }
    int wb = bid - 1024;
    int w = wb >> 8;                        // which weight 0..3
    int t = wb & 255;                       // 64x64 tile over 1024^2
    const float* src = (w == 0) ? Wq : (w == 1) ? Wk : (w == 2) ? Wv : Wo;
    unsigned short* dst = (w < 3) ? WqkvT + (size_t)w * 1024 * DIN : WoT;
    int k0 = (t >> 4) * 64, n0 = (t & 15) * 64;
    // load 64 k-rows x 64 n f32; store col-group swizzled by (r>>3)
#pragma unroll
    for (int j = 0; j < 4; j++) {
        int idx = j * 256 + tid;
        int r = idx >> 4, c4g = idx & 15;
        int sg = c4g ^ ((r >> 3) & 7);
        *reinterpret_cast<float4*>(&tile[r][sg * 4]) =
            *reinterpret_cast<const float4*>(&src[(size_t)(k0 + r) * DOUT + n0 + c4g * 4]);
    }
    __syncthreads();
    // store transposed: element (k, n) lives at tile[k][((n>>2)^(k>>3))*4 + (n&3)]
#pragma unroll
    for (int j = 0; j < 2; j++) {
        int idx = j * 256 + tid;
        int n = idx >> 3, gk = (idx & 7) * 8;
        int g = n >> 2, e = n & 3;
        unsigned short o[8];
#pragma unroll
        for (int u = 0; u < 8; u++) {
            int k = gk + u;
            o[u] = f2b(tile[k][((g ^ ((k >> 3) & 7)) << 2) + e]);
        }
        *reinterpret_cast<int4*>(&dst[(size_t)(n0 + n) * DIN + k0 + gk]) =
            *reinterpret_cast<int4*>(o);
    }
}

// ---------------- bf16 MFMA GEMM: C[M,N] = A[M,K] @ Bt[N,K]^T ----------------
// BM x 128 tile, BK=32, 2-PHASE double-buffered global_load_lds staging
// (STAGE(next) -> compute(cur) -> vmcnt(0)+barrier). T2 XOR swizzle both sides.
// L2-locality grid mapping: each XCD owns a byg x bxg rectangle of tiles
// (A-panel + B-panel working set ~5MB -> mostly L2-resident stage reads).
// OUT_MODE 0: QKV fused — Q/K row-major bf16 (Q pre-scaled by QSCALE);
//             V blocks written TRANSPOSED to Cvt[(b*16+h)*64+hd][s] via LDS.
// OUT_MODE 2: f32 out + bias.
template <int OUT_MODE, int BM>
__global__ __launch_bounds__(256) void k_gemm(const unsigned short* __restrict__ A,
                                              const unsigned short* __restrict__ Bt,
                                              unsigned short* __restrict__ Cq,
                                              unsigned short* __restrict__ Ck,
                                              unsigned short* __restrict__ Cvt,
                                              float* __restrict__ Cf,
                                              const float* __restrict__ bias,
                                              int M, int N, int K, int bxg) {
    constexpr int MI  = BM / 32;            // M-frags per wave
    constexpr int ASZ = BM * 32;            // ushorts per A buffer
    constexpr int BSZ = 128 * 32;
    constexpr int ACH = BM / 64;            // A chunks per wave (1KB each)
    constexpr int STG = 2 * (ASZ + BSZ);
    constexpr int SMEM_N = (OUT_MODE == 0 && STG < 17408) ? 17408 : STG;
    __shared__ __align__(16) unsigned short smem[SMEM_N];

    // 2-D per-XCD tiling: XCDs arranged 4(row-groups) x 2(col-groups).
    int bid = blockIdx.x;
    int xcd = bid & 7;
    int r = bid >> 3;
    int byg = (M / BM) >> 2;                 // by-rows per XCD group
    int by = (xcd >> 1) * byg + r / bxg;
    int bx = (xcd & 1) * bxg + r % bxg;
    int m0 = by * BM, n0 = bx * 128;

    int tid = threadIdx.x;
    int wid = tid >> 6, lane = tid & 63;
    int wm = wid >> 1, wn = wid & 1;
    int lr = lane & 15, lg = lane >> 4;

    f32x4 acc[MI][4] = {};

    int srow = lane >> 2;                           // 0..15 within chunk
    int scol = ((lane & 3) ^ (srow & 3)) * 8;       // pre-swizzled source col
    int runit = (lg ^ (lr & 3)) * 8;                // read-side unit offset

#define STAGE_G(buf, k0)                                                       \
    {                                                                          \
        unsigned short* Ad = smem + (buf) * ASZ;                               \
        unsigned short* Bd = smem + 2 * ASZ + (buf) * BSZ;                     \
        _Pragma("unroll")                                                      \
        for (int c = 0; c < ACH; c++) {                                        \
            int chunk = wid * ACH + c;                                         \
            int row = chunk * 16 + srow;                                       \
            GLDS(A + (size_t)(m0 + row) * K + (k0) + scol,                     \
                 (char*)Ad + chunk * 1024);                                    \
        }                                                                      \
        _Pragma("unroll")                                                      \
        for (int c = 0; c < 2; c++) {                                          \
            int chunk = wid * 2 + c;                                           \
            int row = chunk * 16 + srow;                                       \
            GLDS(Bt + (size_t)(n0 + row) * K + (k0) + scol,                    \
                 (char*)Bd + chunk * 1024);                                    \
        }                                                                      \
    }

    STAGE_G(0, 0)
    __syncthreads();

    int nkt = K >> 5;
    for (int kt = 0; kt < nkt; kt++) {
        int buf = kt & 1;
        if (kt + 1 < nkt) STAGE_G(buf ^ 1, (kt + 1) * 32)

        const unsigned short* Asr = smem + buf * ASZ;
        const unsigned short* Bsr = smem + 2 * ASZ + buf * BSZ;
        bf16x8 af[MI], bf[4];
#pragma unroll
        for (int mi = 0; mi < MI; mi++)
            af[mi] = *reinterpret_cast<const bf16x8*>(
                &Asr[(wm * (BM / 2) + mi * 16 + lr) * 32 + runit]);
#pragma unroll
        for (int ni = 0; ni < 4; ni++)
            bf[ni] = *reinterpret_cast<const bf16x8*>(
                &Bsr[(wn * 64 + ni * 16 + lr) * 32 + runit]);
#pragma unroll
        for (int mi = 0; mi < MI; mi++)
#pragma unroll
            for (int ni = 0; ni < 4; ni++)
                acc[mi][ni] = MFMA(af[mi], bf[ni], acc[mi][ni]);

        asm volatile("s_waitcnt vmcnt(0)" ::: "memory");
        __builtin_amdgcn_s_barrier();
    }

    if (OUT_MODE == 2) {
        for (int mi = 0; mi < MI; mi++)
            for (int ni = 0; ni < 4; ni++)
                for (int i = 0; i < 4; i++) {
                    int row = m0 + wm * (BM / 2) + mi * 16 + lg * 4 + i;
                    int col = n0 + wn * 64 + ni * 16 + lr;
                    Cf[(size_t)row * N + col] = acc[mi][ni][i] + bias[col];
                }
    } else if (n0 < 2048) {
        unsigned short* Cd = (n0 < 1024) ? Cq : Ck;
        int cb = (n0 < 1024) ? 0 : 1024;
        float sc = (n0 < 1024) ? QSCALE : 1.0f;
        for (int mi = 0; mi < MI; mi++)
            for (int ni = 0; ni < 4; ni++)
                for (int i = 0; i < 4; i++) {
                    int row = m0 + wm * (BM / 2) + mi * 16 + lg * 4 + i;
                    int col = n0 + wn * 64 + ni * 16 + lr;
                    Cd[(size_t)row * 1024 + (col - cb)] = f2b(acc[mi][ni][i] * sc);
                }
    } else {
        // V: transpose through LDS (Lt[128 cols][136 rows bf16]) then write
        // coalesced rows of Cvt[(b*16+h)*64+hd][s]. Loop ended with barrier
        // after last compute -> smem reuse safe.
        unsigned short* Lt = smem;
        for (int mi = 0; mi < MI; mi++)
            for (int ni = 0; ni < 4; ni++) {
                int cl = wn * 64 + ni * 16 + lr;
                int rl0 = wm * (BM / 2) + mi * 16 + lg * 4;
                uint2 wd;
                wd.x = pack2(acc[mi][ni][0], acc[mi][ni][1]);
                wd.y = pack2(acc[mi][ni][2], acc[mi][ni][3]);
                *reinterpret_cast<uint2*>(&Lt[cl * 136 + rl0]) = wd;
            }
        __syncthreads();
        int b = m0 >> 11, ms = m0 & (S_ - 1);
        int bh64 = (b * H_ + ((n0 - 2048) >> 6)) * 64;
#pragma unroll
        for (int it = 0; it < 4; it++) {
            int cl = it * 32 + (tid >> 3);
            int ss = (tid & 7) * 16;
            int4 v0 = *reinterpret_cast<int4*>(&Lt[cl * 136 + ss]);
            int4 v1 = *reinterpret_cast<int4*>(&Lt[cl * 136 + ss + 8]);
            unsigned short* dp = Cvt + (size_t)(bh64 + cl) * S_ + ms + ss;
            *reinterpret_cast<int4*>(dp) = v0;
            *reinterpret_cast<int4*>(dp + 8) = v1;
        }
    }
#undef STAGE_G
}

// ---------------- flash attention (causal), 8-wave paired blocks ----------------
// 1-D grid of 512 blocks with XCD-aware (T1) bijective swizzle: with the
// hardware's bid%8 round-robin, xcd = bid&7 selects a group of 4 bh, so each
// XCD's 64 resident blocks share 4 heads -> KV working set 2MB <= 4MB L2.
// Waves 0-3: q-tile 31-p; waves 4-7: q-tile p. QUAD-buffered KV stream,
// single barrier per iteration (race-free: stage(t+2) writes buf((t-2)%4)
// whose last reader precedes barrier(t-1) in program order). vmcnt counted.
// Boundless exp2-softmax, per-lane l accumulation.
__global__ __launch_bounds__(512, 4) void k_attn(const unsigned short* __restrict__ Q,
                                                 const unsigned short* __restrict__ Kg,
                                                 const unsigned short* __restrict__ Vt,
                                                 unsigned short* __restrict__ ctx) {
    int bid = blockIdx.x;
    int xcd = bid & 7;
    int k   = bid >> 3;          // 0..63
    int p   = k >> 2;            // 0..15
    int bh  = xcd * 4 + (k & 3); // 0..31, grouped 4-per-XCD
    int b = bh >> 4, h = bh & 15;
    int tid = threadIdx.x, wid = tid >> 6, lane = tid & 63;
    int lr = lane & 15, lg = lane >> 4;
    int qtB = 31 - p;
    int qt = (wid < 4) ? qtB : p;          // wave's own q-tile
    int q0 = qt * 64 + (wid & 3) * 16;     // wave's 16 q-rows

    __shared__ __align__(16) unsigned short Ks[4][64 * 64];   // [kv][hd], swizzled
    __shared__ __align__(16) unsigned short Vs[4][64 * 64];   // [hd][s],  swizzled
    __shared__ __align__(16) unsigned p_lds32[8][16 * 32];    // per-wave P
    unsigned* pl32 = p_lds32[wid];

    const unsigned short* Qp = Q  + (size_t)b * S_ * DOUT + (size_t)h * HD_;
    const unsigned short* Kp = Kg + (size_t)b * S_ * DOUT + (size_t)h * HD_;
    const unsigned short* Vp = Vt + (size_t)(b * H_ + h) * HD_ * S_;

    bf16x8 qf0 = *reinterpret_cast<const bf16x8*>(&Qp[(size_t)(q0 + lr) * DOUT + lg * 8]);
    bf16x8 qf1 = *reinterpret_cast<const bf16x8*>(&Qp[(size_t)(q0 + lr) * DOUT + 32 + lg * 8]);
    asm volatile("" : "+v"(qf0), "+v"(qf1));

    int srow = lane >> 3;
    int scol = ((lane & 7) ^ srow) * 8;        // pre-swizzled col (elements)

#define STAGE_KV(buf, t)                                                           \
    {                                                                              \
        int kv0_ = (t) * 64;                                                       \
        int krow = wid * 8 + srow;                                                 \
        GLDS(Kp + (size_t)(kv0_ + krow) * DOUT + scol,                             \
             (char*)&Ks[buf][0] + wid * 1024);                                     \
        GLDS(Vp + (size_t)krow * S_ + kv0_ + scol,                                 \
             (char*)&Vs[buf][0] + wid * 1024);                                     \
    }

    int ntile = qtB + 1;   // >= 17
    STAGE_KV(0, 0)
    STAGE_KV(1, 1)

    f32x4 o[4] = {};
    float l = 0.f;
    int rxor = (lr & 7) << 4;
    int qg = q0 + lr;

    int cur = 0;           // t % 4
    for (int t = 0; t < ntile; t++) {
        int ahead = ntile - 1 - t;
        if (ahead >= 2) {
            STAGE_KV((cur + 2) & 3, t + 2)
            asm volatile("s_waitcnt vmcnt(4)" ::: "memory");
        } else if (ahead == 1) {
            asm volatile("s_waitcnt vmcnt(2)" ::: "memory");
        } else {
            asm volatile("s_waitcnt vmcnt(0)" ::: "memory");
        }
        __builtin_amdgcn_s_barrier();

        if (t <= qt) {
            const unsigned short* Kt = Ks[cur];
            const unsigned short* Vl = Vs[cur];
            int kv0 = t * 64;

            // QK^T swapped: mfma(K, Q) -> lane owns q-row (q0+lr)
            f32x4 s[4] = {};
            __builtin_amdgcn_s_setprio(1);
#pragma unroll
            for (int nf = 0; nf < 4; nf++)
#pragma unroll
                for (int kk = 0; kk < 2; kk++) {
                    bf16x8 kf = *reinterpret_cast<const bf16x8*>(
                        &Kt[(nf * 16 + lr) * 64 + (((kk * 64 + lg * 16) ^ rxor) >> 1)]);
                    s[nf] = MFMA(kf, kk ? qf1 : qf0, s[nf]);
                }
            __builtin_amdgcn_s_setprio(0);

            if (t == qt) {
#pragma unroll
                for (int nf = 0; nf < 4; nf++)
#pragma unroll
                    for (int i = 0; i < 4; i++)
                        if (kv0 + nf * 16 + lg * 4 + i > qg) s[nf][i] = -2000.0f;
            }

            // boundless softmax: P = exp2(s), pack to bf16, swizzled P-LDS
            f32x4 acc = {};
#pragma unroll
            for (int nf = 0; nf < 4; nf++) {
                f32x4 pv;
#pragma unroll
                for (int i = 0; i < 4; i++) pv[i] = exp2f(s[nf][i]);
                acc += pv;
                int unit = (nf * 2 + (lg >> 1)) ^ (lr & 7);
                uint2 wd; wd.x = pack2(pv[0], pv[1]); wd.y = pack2(pv[2], pv[3]);
                *reinterpret_cast<uint2*>(&pl32[lr * 32 + unit * 4 + (lg & 1) * 2]) = wd;
            }
            l += (acc[0] + acc[1]) + (acc[2] + acc[3]);

            bf16x8 pf[2];
#pragma unroll
            for (int kvb = 0; kvb < 2; kvb++)
                pf[kvb] = *reinterpret_cast<const bf16x8*>(
                    &pl32[lr * 32 + (((kvb * 4 + lg) ^ (lr & 7)) * 4)]);

            // PV
            __builtin_amdgcn_s_setprio(1);
#pragma unroll
            for (int nd = 0; nd < 4; nd++)
#pragma unroll
                for (int kk = 0; kk < 2; kk++) {
                    bf16x8 vf = *reinterpret_cast<const bf16x8*>(
                        &Vl[(nd * 16 + lr) * 64 + (((kk * 64 + lg * 16) ^ rxor) >> 1)]);
                    o[nd] = MFMA(pf[kk], vf, o[nd]);
                }
            __builtin_amdgcn_s_setprio(0);
        }

        cur = (cur + 1) & 3;
    }

    // cross-lane row sums (hoisted out of the KV loop)
    l += __shfl_xor(l, 16, 64);
    l += __shfl_xor(l, 32, 64);

#pragma unroll
    for (int i = 0; i < 4; i++) {
        float li = __shfl(l, lg * 4 + i, 16);
        float r = __builtin_amdgcn_rcpf(li);
#pragma unroll
        for (int nd = 0; nd < 4; nd++)
            ((__bf16*)ctx)[((size_t)b * S_ + q0 + lg * 4 + i) * DOUT + h * HD_ + nd * 16 + lr] =
                (__bf16)(o[nd][i] * r);
    }
#undef STAGE_KV
}

extern "C" void kernel_launch(void* const* d_in, const int* in_sizes, int n_in,
                              void* d_out, int out_size, void* d_ws, size_t ws_size,
                              hipStream_t stream) {
    const float* x  = (const float*)d_in[0];
    const float* Wq = (const float*)d_in[1];
    const float* Wk = (const float*)d_in[2];
    const float* Wv = (const float*)d_in[3];
    const float* Wo = (const float*)d_in[4];
    const float* bo = (const float*)d_in[5];
    float* out = (float*)d_out;
    char* ws = (char*)d_ws;
    const size_t MB = 1u << 20;

    // layout (40 MB): xb@0 (ctx reuses after QKV), WqkvT@8, WoT@14,
    // Qb@16, Kb@24, Vtb@32 (written transposed by QKV epilogue).
    unsigned short* xb    = (unsigned short*)(ws);
    unsigned short* ctx   = (unsigned short*)(ws);            // reuse of xb
    unsigned short* WqkvT = (unsigned short*)(ws + 8 * MB);
    unsigned short* WoT   = (unsigned short*)(ws + 14 * MB);
    unsigned short* Qb    = (unsigned short*)(ws + 16 * MB);
    unsigned short* Kb    = (unsigned short*)(ws + 24 * MB);
    unsigned short* Vtb   = (unsigned short*)(ws + 32 * MB);

    (void)in_sizes; (void)n_in; (void)out_size; (void)ws_size;

    // fused converts: x -> bf16, 4 weights -> bf16 transposed
    k_cvt_all<<<2048, 256, 0, stream>>>(x, Wq, Wk, Wv, Wo, xb, WqkvT, WoT);

    // fused QKV projection (Q pre-scaled; V written transposed -> no trV pass)
    // per-XCD tile rectangle: 8 by x 12 bx (A 2MB + B 3MB working set)
    k_gemm<0, 128><<<768, 256, 0, stream>>>(xb, WqkvT, Qb, Kb, Vtb, nullptr, nullptr,
                                            M_, 3072, DIN, 12);

    // causal flash attention: XCD-swizzled 1-D grid, quad-buffered single-barrier
    k_attn<<<512, 512, 0, stream>>>(Qb, Kb, Vtb, ctx);

    // output projection + bias; per-XCD rectangle: 16 by x 4 bx
    k_gemm<2, 64><<<512, 256, 0, stream>>>(ctx, WoT, nullptr, nullptr, nullptr,
                                           out, bo, M_, DOUT, DOUT, 4);
}

// Round 18
// 100.354 us; speedup vs baseline: 1.0270x; 1.0067x over previous
//
#include <hip/hip_runtime.h>

// Problem constants
#define B_    2
#define S_    2048
#define DIN   1024
#define DOUT  1024
#define H_    16
#define HD_   64
#define M_    (B_ * S_)   // 4096 rows total

typedef __bf16 bf16x8 __attribute__((ext_vector_type(8)));
typedef float  f32x4  __attribute__((ext_vector_type(4)));

__device__ __forceinline__ f32x4 MFMA(bf16x8 a, bf16x8 b, f32x4 c) {
    return __builtin_amdgcn_mfma_f32_16x16x32_bf16(a, b, c, 0, 0, 0);
}

// float -> bf16 bits, round-to-nearest-even
__device__ __forceinline__ unsigned short f2b(float f) {
    union { float f; unsigned int u; } v; v.f = f;
    unsigned int u = v.u;
    return (unsigned short)((u + 0x7fffu + ((u >> 16) & 1u)) >> 16);
}

// pack two floats into one u32 of bf16 pairs (lo = a, hi = b)
__device__ __forceinline__ unsigned pack2(float a, float b) {
    union { __bf16 h[2]; unsigned u; } cv;
    cv.h[0] = (__bf16)a; cv.h[1] = (__bf16)b;
    return cv.u;
}

// async global->LDS, 16B per lane; LDS dest = wave-uniform base + lane*16
#define GLDS(gp, lp) __builtin_amdgcn_global_load_lds( \
    (const __attribute__((address_space(1))) void*)(gp), \
    (__attribute__((address_space(3))) void*)(lp), 16, 0, 0)

// Q pre-scale: 1/sqrt(64) * log2(e)  (exp2-domain softmax)
#define QSCALE 0.1803368801111204f

// ---- fused converts, vectorized ----
// grid [0,1024): x f32->bf16, 16 elems/thread.
// grid [1024,2048): weight transpose 64x64 f32 tiles, float4 in / ushort8 out.
// Transpose-read conflict fix: column-group XOR'd with row>>3 (both sides).
__global__ __launch_bounds__(256) void k_cvt_all(const float* __restrict__ x,
                                                 const float* __restrict__ Wq,
                                                 const float* __restrict__ Wk,
                                                 const float* __restrict__ Wv,
                                                 const float* __restrict__ Wo,
                                                 unsigned short* __restrict__ xb,
                                                 unsigned short* __restrict__ WqkvT,
                                                 unsigned short* __restrict__ WoT) {
    __shared__ __align__(16) float tile[64][68];
    int bid = blockIdx.x;
    int tid = threadIdx.x;
    if (bid < 1024) {
#pragma unroll
        for (int j = 0; j < 4; j++) {
            int i = bid * 4096 + j * 1024 + tid * 4;
            float4 v = *reinterpret_cast<const float4*>(x + i);
            ushort4 o;
            o.x = f2b(v.x); o.y = f2b(v.y); o.z = f2b(v.z); o.w = f2b(v.w);
            *reinterpret_cast<ushort4*>(xb + i) = o;
        }
        return;
    }
    int wb = bid - 1024;
    int w = wb >> 8;                        // which weight 0..3
    int t = wb & 255;                       // 64x64 tile over 1024^2
    const float* src = (w == 0) ? Wq : (w == 1) ? Wk : (w == 2) ? Wv : Wo;
    unsigned short* dst = (w < 3) ? WqkvT + (size_t)w * 1024 * DIN : WoT;
    int k0 = (t >> 4) * 64, n0 = (t & 15) * 64;
    // load 64 k-rows x 64 n f32; store col-group swizzled by (r>>3)
#pragma unroll
    for (int j = 0; j < 4; j++) {
        int idx = j * 256 + tid;
        int r = idx >> 4, c4g = idx & 15;
        int sg = c4g ^ ((r >> 3) & 7);
        *reinterpret_cast<float4*>(&tile[r][sg * 4]) =
            *reinterpret_cast<const float4*>(&src[(size_t)(k0 + r) * DOUT + n0 + c4g * 4]);
    }
    __syncthreads();
    // store transposed: element (k, n) lives at tile[k][((n>>2)^(k>>3))*4 + (n&3)]
#pragma unroll
    for (int j = 0; j < 2; j++) {
        int idx = j * 256 + tid;
        int n = idx >> 3, gk = (idx & 7) * 8;
        int g = n >> 2, e = n & 3;
        unsigned short o[8];
#pragma unroll
        for (int u = 0; u < 8; u++) {
            int k = gk + u;
            o[u] = f2b(tile[k][((g ^ ((k >> 3) & 7)) << 2) + e]);
        }
        *reinterpret_cast<int4*>(&dst[(size_t)(n0 + n) * DIN + k0 + gk]) =
            *reinterpret_cast<int4*>(o);
    }
}

// ---------------- bf16 MFMA GEMM: C[M,N] = A[M,K] @ Bt[N,K]^T ----------------
// BM x 128 tile, BK=32, TRIPLE-buffered global_load_lds staging with counted
// vmcnt (T4), 1-ahead: stage(t+1) -> vmcnt(L) -> barrier -> compute(t).
// The wait targets stage(t), issued a FULL iteration earlier -> nearly free;
// never drains to 0 mid-loop. Race-free: stage(t+1) overwrites buf(t-2),
// whose last reader compute(t-2) precedes barrier(t-1) in program order.
// LDS 49KB (BM=128) -> 3 blocks/CU = grid residency -> no occupancy cost.
// T2 XOR swizzle both sides; 2-D per-XCD tile rectangles for L2 locality.
// OUT_MODE 0: QKV fused — Q/K row-major bf16 (Q pre-scaled by QSCALE);
//             V blocks written TRANSPOSED to Cvt[(b*16+h)*64+hd][s] via LDS.
// OUT_MODE 2: f32 out + bias.
template <int OUT_MODE, int BM>
__global__ __launch_bounds__(256) void k_gemm(const unsigned short* __restrict__ A,
                                              const unsigned short* __restrict__ Bt,
                                              unsigned short* __restrict__ Cq,
                                              unsigned short* __restrict__ Ck,
                                              unsigned short* __restrict__ Cvt,
                                              float* __restrict__ Cf,
                                              const float* __restrict__ bias,
                                              int M, int N, int K, int bxg) {
    constexpr int MI  = BM / 32;            // M-frags per wave
    constexpr int ASZ = BM * 32;            // ushorts per A buffer
    constexpr int BSZ = 128 * 32;
    constexpr int ACH = BM / 64;            // A chunks per wave (1KB each)
    constexpr int STG = 3 * (ASZ + BSZ);    // triple-buffered
    constexpr int SMEM_N = (OUT_MODE == 0 && STG < 17408) ? 17408 : STG;
    __shared__ __align__(16) unsigned short smem[SMEM_N];

    // 2-D per-XCD tiling: XCDs arranged 4(row-groups) x 2(col-groups).
    int bid = blockIdx.x;
    int xcd = bid & 7;
    int r = bid >> 3;
    int byg = (M / BM) >> 2;                 // by-rows per XCD group
    int by = (xcd >> 1) * byg + r / bxg;
    int bx = (xcd & 1) * bxg + r % bxg;
    int m0 = by * BM, n0 = bx * 128;

    int tid = threadIdx.x;
    int wid = tid >> 6, lane = tid & 63;
    int wm = wid >> 1, wn = wid & 1;
    int lr = lane & 15, lg = lane >> 4;

    f32x4 acc[MI][4] = {};

    int srow = lane >> 2;                           // 0..15 within chunk
    int scol = ((lane & 3) ^ (srow & 3)) * 8;       // pre-swizzled source col
    int runit = (lg ^ (lr & 3)) * 8;                // read-side unit offset

#define STAGE_G(buf, k0)                                                       \
    {                                                                          \
        unsigned short* Ad = smem + (buf) * ASZ;                               \
        unsigned short* Bd = smem + 3 * ASZ + (buf) * BSZ;                     \
        _Pragma("unroll")                                                      \
        for (int c = 0; c < ACH; c++) {                                        \
            int chunk = wid * ACH + c;                                         \
            int row = chunk * 16 + srow;                                       \
            GLDS(A + (size_t)(m0 + row) * K + (k0) + scol,                     \
                 (char*)Ad + chunk * 1024);                                    \
        }                                                                      \
        _Pragma("unroll")                                                      \
        for (int c = 0; c < 2; c++) {                                          \
            int chunk = wid * 2 + c;                                           \
            int row = chunk * 16 + srow;                                       \
            GLDS(Bt + (size_t)(n0 + row) * K + (k0) + scol,                    \
                 (char*)Bd + chunk * 1024);                                    \
        }                                                                      \
    }

    int nkt = K >> 5;
    STAGE_G(0, 0)

    int cur = 0;
    for (int kt = 0; kt < nkt; kt++) {
        if (kt + 1 < nkt) {
            int nb = cur + 1; if (nb >= 3) nb -= 3;
            STAGE_G(nb, (kt + 1) * 32)
            if constexpr (BM == 128) { asm volatile("s_waitcnt vmcnt(4)" ::: "memory"); }
            else                     { asm volatile("s_waitcnt vmcnt(3)" ::: "memory"); }
        } else {
            asm volatile("s_waitcnt vmcnt(0)" ::: "memory");
        }
        __builtin_amdgcn_s_barrier();

        const unsigned short* Asr = smem + cur * ASZ;
        const unsigned short* Bsr = smem + 3 * ASZ + cur * BSZ;
        bf16x8 af[MI], bf[4];
#pragma unroll
        for (int mi = 0; mi < MI; mi++)
            af[mi] = *reinterpret_cast<const bf16x8*>(
                &Asr[(wm * (BM / 2) + mi * 16 + lr) * 32 + runit]);
#pragma unroll
        for (int ni = 0; ni < 4; ni++)
            bf[ni] = *reinterpret_cast<const bf16x8*>(
                &Bsr[(wn * 64 + ni * 16 + lr) * 32 + runit]);
#pragma unroll
        for (int mi = 0; mi < MI; mi++)
#pragma unroll
            for (int ni = 0; ni < 4; ni++)
                acc[mi][ni] = MFMA(af[mi], bf[ni], acc[mi][ni]);

        cur = cur + 1; if (cur >= 3) cur -= 3;
    }

    if (OUT_MODE == 2) {
        for (int mi = 0; mi < MI; mi++)
            for (int ni = 0; ni < 4; ni++)
                for (int i = 0; i < 4; i++) {
                    int row = m0 + wm * (BM / 2) + mi * 16 + lg * 4 + i;
                    int col = n0 + wn * 64 + ni * 16 + lr;
                    Cf[(size_t)row * N + col] = acc[mi][ni][i] + bias[col];
                }
    } else if (n0 < 2048) {
        unsigned short* Cd = (n0 < 1024) ? Cq : Ck;
        int cb = (n0 < 1024) ? 0 : 1024;
        float sc = (n0 < 1024) ? QSCALE : 1.0f;
        for (int mi = 0; mi < MI; mi++)
            for (int ni = 0; ni < 4; ni++)
                for (int i = 0; i < 4; i++) {
                    int row = m0 + wm * (BM / 2) + mi * 16 + lg * 4 + i;
                    int col = n0 + wn * 64 + ni * 16 + lr;
                    Cd[(size_t)row * 1024 + (col - cb)] = f2b(acc[mi][ni][i] * sc);
                }
    } else {
        // V: transpose through LDS (Lt[128 cols][136 rows bf16]) then write
        // coalesced rows of Cvt[(b*16+h)*64+hd][s]. Other waves may still be
        // reading staging buffers -> barrier before reuse.
        __syncthreads();
        unsigned short* Lt = smem;
        for (int mi = 0; mi < MI; mi++)
            for (int ni = 0; ni < 4; ni++) {
                int cl = wn * 64 + ni * 16 + lr;
                int rl0 = wm * (BM / 2) + mi * 16 + lg * 4;
                uint2 wd;
                wd.x = pack2(acc[mi][ni][0], acc[mi][ni][1]);
                wd.y = pack2(acc[mi][ni][2], acc[mi][ni][3]);
                *reinterpret_cast<uint2*>(&Lt[cl * 136 + rl0]) = wd;
            }
        __syncthreads();
        int b = m0 >> 11, ms = m0 & (S_ - 1);
        int bh64 = (b * H_ + ((n0 - 2048) >> 6)) * 64;
#pragma unroll
        for (int it = 0; it < 4; it++) {
            int cl = it * 32 + (tid >> 3);
            int ss = (tid & 7) * 16;
            int4 v0 = *reinterpret_cast<int4*>(&Lt[cl * 136 + ss]);
            int4 v1 = *reinterpret_cast<int4*>(&Lt[cl * 136 + ss + 8]);
            unsigned short* dp = Cvt + (size_t)(bh64 + cl) * S_ + ms + ss;
            *reinterpret_cast<int4*>(dp) = v0;
            *reinterpret_cast<int4*>(dp + 8) = v1;
        }
    }
#undef STAGE_G
}

// ---------------- flash attention (causal), 8-wave paired blocks ----------------
// 1-D grid of 512 blocks with XCD-aware (T1) bijective swizzle: with the
// hardware's bid%8 round-robin, xcd = bid&7 selects a group of 4 bh, so each
// XCD's 64 resident blocks share 4 heads -> KV working set 2MB <= 4MB L2.
// Waves 0-3: q-tile 31-p; waves 4-7: q-tile p. QUAD-buffered KV stream,
// single barrier per iteration (race-free: stage(t+2) writes buf((t-2)%4)
// whose last reader precedes barrier(t-1) in program order). vmcnt counted.
// Boundless exp2-softmax, per-lane l accumulation.
__global__ __launch_bounds__(512, 4) void k_attn(const unsigned short* __restrict__ Q,
                                                 const unsigned short* __restrict__ Kg,
                                                 const unsigned short* __restrict__ Vt,
                                                 unsigned short* __restrict__ ctx) {
    int bid = blockIdx.x;
    int xcd = bid & 7;
    int k   = bid >> 3;          // 0..63
    int p   = k >> 2;            // 0..15
    int bh  = xcd * 4 + (k & 3); // 0..31, grouped 4-per-XCD
    int b = bh >> 4, h = bh & 15;
    int tid = threadIdx.x, wid = tid >> 6, lane = tid & 63;
    int lr = lane & 15, lg = lane >> 4;
    int qtB = 31 - p;
    int qt = (wid < 4) ? qtB : p;          // wave's own q-tile
    int q0 = qt * 64 + (wid & 3) * 16;     // wave's 16 q-rows

    __shared__ __align__(16) unsigned short Ks[4][64 * 64];   // [kv][hd], swizzled
    __shared__ __align__(16) unsigned short Vs[4][64 * 64];   // [hd][s],  swizzled
    __shared__ __align__(16) unsigned p_lds32[8][16 * 32];    // per-wave P
    unsigned* pl32 = p_lds32[wid];

    const unsigned short* Qp = Q  + (size_t)b * S_ * DOUT + (size_t)h * HD_;
    const unsigned short* Kp = Kg + (size_t)b * S_ * DOUT + (size_t)h * HD_;
    const unsigned short* Vp = Vt + (size_t)(b * H_ + h) * HD_ * S_;

    bf16x8 qf0 = *reinterpret_cast<const bf16x8*>(&Qp[(size_t)(q0 + lr) * DOUT + lg * 8]);
    bf16x8 qf1 = *reinterpret_cast<const bf16x8*>(&Qp[(size_t)(q0 + lr) * DOUT + 32 + lg * 8]);
    asm volatile("" : "+v"(qf0), "+v"(qf1));

    int srow = lane >> 3;
    int scol = ((lane & 7) ^ srow) * 8;        // pre-swizzled col (elements)

#define STAGE_KV(buf, t)                                                           \
    {                                                                              \
        int kv0_ = (t) * 64;                                                       \
        int krow = wid * 8 + srow;                                                 \
        GLDS(Kp + (size_t)(kv0_ + krow) * DOUT + scol,                             \
             (char*)&Ks[buf][0] + wid * 1024);                                     \
        GLDS(Vp + (size_t)krow * S_ + kv0_ + scol,                                 \
             (char*)&Vs[buf][0] + wid * 1024);                                     \
    }

    int ntile = qtB + 1;   // >= 17
    STAGE_KV(0, 0)
    STAGE_KV(1, 1)

    f32x4 o[4] = {};
    float l = 0.f;
    int rxor = (lr & 7) << 4;
    int qg = q0 + lr;

    int cur = 0;           // t % 4
    for (int t = 0; t < ntile; t++) {
        int ahead = ntile - 1 - t;
        if (ahead >= 2) {
            STAGE_KV((cur + 2) & 3, t + 2)
            asm volatile("s_waitcnt vmcnt(4)" ::: "memory");
        } else if (ahead == 1) {
            asm volatile("s_waitcnt vmcnt(2)" ::: "memory");
        } else {
            asm volatile("s_waitcnt vmcnt(0)" ::: "memory");
        }
        __builtin_amdgcn_s_barrier();

        if (t <= qt) {
            const unsigned short* Kt = Ks[cur];
            const unsigned short* Vl = Vs[cur];
            int kv0 = t * 64;

            // QK^T swapped: mfma(K, Q) -> lane owns q-row (q0+lr)
            f32x4 s[4] = {};
            __builtin_amdgcn_s_setprio(1);
#pragma unroll
            for (int nf = 0; nf < 4; nf++)
#pragma unroll
                for (int kk = 0; kk < 2; kk++) {
                    bf16x8 kf = *reinterpret_cast<const bf16x8*>(
                        &Kt[(nf * 16 + lr) * 64 + (((kk * 64 + lg * 16) ^ rxor) >> 1)]);
                    s[nf] = MFMA(kf, kk ? qf1 : qf0, s[nf]);
                }
            __builtin_amdgcn_s_setprio(0);

            if (t == qt) {
#pragma unroll
                for (int nf = 0; nf < 4; nf++)
#pragma unroll
                    for (int i = 0; i < 4; i++)
                        if (kv0 + nf * 16 + lg * 4 + i > qg) s[nf][i] = -2000.0f;
            }

            // boundless softmax: P = exp2(s), pack to bf16, swizzled P-LDS
            f32x4 acc = {};
#pragma unroll
            for (int nf = 0; nf < 4; nf++) {
                f32x4 pv;
#pragma unroll
                for (int i = 0; i < 4; i++) pv[i] = exp2f(s[nf][i]);
                acc += pv;
                int unit = (nf * 2 + (lg >> 1)) ^ (lr & 7);
                uint2 wd; wd.x = pack2(pv[0], pv[1]); wd.y = pack2(pv[2], pv[3]);
                *reinterpret_cast<uint2*>(&pl32[lr * 32 + unit * 4 + (lg & 1) * 2]) = wd;
            }
            l += (acc[0] + acc[1]) + (acc[2] + acc[3]);

            bf16x8 pf[2];
#pragma unroll
            for (int kvb = 0; kvb < 2; kvb++)
                pf[kvb] = *reinterpret_cast<const bf16x8*>(
                    &pl32[lr * 32 + (((kvb * 4 + lg) ^ (lr & 7)) * 4)]);

            // PV
            __builtin_amdgcn_s_setprio(1);
#pragma unroll
            for (int nd = 0; nd < 4; nd++)
#pragma unroll
                for (int kk = 0; kk < 2; kk++) {
                    bf16x8 vf = *reinterpret_cast<const bf16x8*>(
                        &Vl[(nd * 16 + lr) * 64 + (((kk * 64 + lg * 16) ^ rxor) >> 1)]);
                    o[nd] = MFMA(pf[kk], vf, o[nd]);
                }
            __builtin_amdgcn_s_setprio(0);
        }

        cur = (cur + 1) & 3;
    }

    // cross-lane row sums (hoisted out of the KV loop)
    l += __shfl_xor(l, 16, 64);
    l += __shfl_xor(l, 32, 64);

#pragma unroll
    for (int i = 0; i < 4; i++) {
        float li = __shfl(l, lg * 4 + i, 16);
        float r = __builtin_amdgcn_rcpf(li);
#pragma unroll
        for (int nd = 0; nd < 4; nd++)
            ((__bf16*)ctx)[((size_t)b * S_ + q0 + lg * 4 + i) * DOUT + h * HD_ + nd * 16 + lr] =
                (__bf16)(o[nd][i] * r);
    }
#undef STAGE_KV
}

extern "C" void kernel_launch(void* const* d_in, const int* in_sizes, int n_in,
                              void* d_out, int out_size, void* d_ws, size_t ws_size,
                              hipStream_t stream) {
    const float* x  = (const float*)d_in[0];
    const float* Wq = (const float*)d_in[1];
    const float* Wk = (const float*)d_in[2];
    const float* Wv = (const float*)d_in[3];
    const float* Wo = (const float*)d_in[4];
    const float* bo = (const float*)d_in[5];
    float* out = (float*)d_out;
    char* ws = (char*)d_ws;
    const size_t MB = 1u << 20;

    // layout (40 MB): xb@0 (ctx reuses after QKV), WqkvT@8, WoT@14,
    // Qb@16, Kb@24, Vtb@32 (written transposed by QKV epilogue).
    unsigned short* xb    = (unsigned short*)(ws);
    unsigned short* ctx   = (unsigned short*)(ws);            // reuse of xb
    unsigned short* WqkvT = (unsigned short*)(ws + 8 * MB);
    unsigned short* WoT   = (unsigned short*)(ws + 14 * MB);
    unsigned short* Qb    = (unsigned short*)(ws + 16 * MB);
    unsigned short* Kb    = (unsigned short*)(ws + 24 * MB);
    unsigned short* Vtb   = (unsigned short*)(ws + 32 * MB);

    (void)in_sizes; (void)n_in; (void)out_size; (void)ws_size;

    // fused converts: x -> bf16, 4 weights -> bf16 transposed
    k_cvt_all<<<2048, 256, 0, stream>>>(x, Wq, Wk, Wv, Wo, xb, WqkvT, WoT);

    // fused QKV projection (Q pre-scaled; V written transposed -> no trV pass)
    // per-XCD tile rectangle: 8 by x 12 bx (A 2MB + B 3MB working set)
    k_gemm<0, 128><<<768, 256, 0, stream>>>(xb, WqkvT, Qb, Kb, Vtb, nullptr, nullptr,
                                            M_, 3072, DIN, 12);

    // causal flash attention: XCD-swizzled 1-D grid, quad-buffered single-barrier
    k_attn<<<512, 512, 0, stream>>>(Qb, Kb, Vtb, ctx);

    // output projection + bias; per-XCD rectangle: 16 by x 4 bx
    k_gemm<2, 64><<<512, 256, 0, stream>>>(ctx, WoT, nullptr, nullptr, nullptr,
                                           out, bo, M_, DOUT, DOUT, 4);
}